// Round 3
// baseline (56682.043 us; speedup 1.0000x reference)
//
#include <hip/hip_runtime.h>
#include <math.h>

// SynchronGRU R10: fit the working set in ARCHITECTED VGPRs.
// R9 (3.75 ms) kept 192 weights/thread at 512 threads: RA reported only 128
// VGPRs (256-unified budget) -> 128V+128A split; every weight FMA paid an
// extra accvgpr move/reload => VALU issue 3.0 ms vs 1.31 ms pure-FMA floor
// (2.3x). FETCH/WRITE +230 MB = once-per-layer spill round-trips.
// R10: 768 threads (12 waves, 3/SIMD, __launch_bounds__(768,3) -> 170 VGPR
// cap). Thread (kq=wave&3, c=64*(wave>>2)+lane in [0,192)) owns cols
// {c, c+192} x k-rows [32kq,32kq+32) of BOTH matrices = 128 resident floats
// + 8 accumulators; everything architected, no AGPR traffic. 256 FMA/thread/
// step (same 1.31 ms floor, 3-wave TLP). Weight indices all compile-time
// (full unroll; runtime-indexed arrays go to scratch). Layer 0 runs h-only
// + 8-row x fix-up (skips 24 all-zero x-rows, ~6% of FLOPs). Biases + h
// live in LDS so gate-only state doesn't inflate the uniform VGPR budget.

namespace {

constexpr int kB = 512;
constexpr int kT = 256;
constexpr int kF = 8;
constexpr int kU = 128;
constexpr int kG = 384;   // 3*U, gate order [z, r, h]
constexpr int kL = 8;
constexpr int kRows = 2;       // batch rows per block
constexpr int kThreads = 768;  // 12 waves, 3 per SIMD
constexpr int kSt = 8;         // time-steps per x staging chunk

// LDS layout (floats)
constexpr int kOffXstage = 0;                    // [2r][8t][128] = 2048
constexpr int kOffHbuf   = 2 * kSt * kU;         // [2r][128]     = 256   (2048)
constexpr int kOffPacc   = kOffHbuf + 2 * kU;    // [4kq][2r][2s][384] = 6144 (2304)
constexpr int kOffBiasx  = kOffPacc + 16 * kG;   // [384] (8448)
constexpr int kOffBiash  = kOffBiasx + kG;       // [384] (8832)
constexpr int kSmemFloats = kOffBiash + kG;      // 9216 floats = 36 KB
static_assert(kSmemFloats * 4 <= 160 * 1024, "LDS budget");

__device__ __forceinline__ float frcp(float x) { return __builtin_amdgcn_rcpf(x); }

// h-side only: 16 FMA per quad (k4 must be a literal: weight regs need
// compile-time indices or they spill to scratch)
#define DOT_H(k4)                                                             \
    {                                                                         \
        const float4 hv0 = hs0[(k4)];                                         \
        const float4 hv1 = hs1[(k4)];                                         \
        const float h0[4] = {hv0.x, hv0.y, hv0.z, hv0.w};                     \
        const float h1[4] = {hv1.x, hv1.y, hv1.z, hv1.w};                     \
        _Pragma("unroll")                                                     \
        for (int j = 0; j < 4; ++j) {                                         \
            const int i = 4 * (k4) + j;                                       \
            ahA0 += whA[i] * h0[j]; ahA1 += whA[i] * h1[j];                   \
            ahB0 += whB[i] * h0[j]; ahB1 += whB[i] * h1[j];                   \
        }                                                                     \
    }

// x-side only: 16 FMA per quad
#define DOT_X(k4)                                                             \
    {                                                                         \
        const float4 xv0 = xs0[(k4)];                                         \
        const float4 xv1 = xs1[(k4)];                                         \
        const float x0[4] = {xv0.x, xv0.y, xv0.z, xv0.w};                     \
        const float x1[4] = {xv1.x, xv1.y, xv1.z, xv1.w};                     \
        _Pragma("unroll")                                                     \
        for (int j = 0; j < 4; ++j) {                                         \
            const int i = 4 * (k4) + j;                                       \
            axA0 += wxA[i] * x0[j]; axA1 += wxA[i] * x1[j];                   \
            axB0 += wxB[i] * x0[j]; axB1 += wxB[i] * x1[j];                   \
        }                                                                     \
    }

__global__ __launch_bounds__(kThreads, 3) void gru_all(
    const float* __restrict__ xin,      // (B,T,F)
    const float* __restrict__ init_h,   // (L,B,U)
    const float* __restrict__ kernel0,  // (F,3U)
    const float* __restrict__ kernels,  // (L-1,U,3U)
    const float* __restrict__ rec_k,    // (L,U,3U)
    const float* __restrict__ biases,   // (L,2,3U)
    float* __restrict__ out)            // (B,T,U) seq out | (L,B,U) states
{
    __shared__ __align__(16) float smem[kSmemFloats];
    float* xstage = smem + kOffXstage;
    float* hbuf   = smem + kOffHbuf;
    float* pacc   = smem + kOffPacc;   // idx = ((kq*2+r)*2+side)*kG + col, side 0=x 1=h
    float* biasx  = smem + kOffBiasx;
    float* biash  = smem + kOffBiash;

    const int tid  = threadIdx.x;
    const int b0   = blockIdx.x * kRows;
    const int wv   = tid >> 6;            // wave 0..11
    const int lane = tid & 63;
    const int kq   = wv & 3;              // wave-uniform k-quarter
    const int c    = ((wv >> 2) << 6) + lane;  // 0..191; owns cols {c, c+192}

    const int gr = (tid >> 7) & 1;  // gate-phase row  (valid tid<256)
    const int gu = tid & 127;       // gate-phase unit

    float* __restrict__ buf    = out;                        // in-place activations
    float* __restrict__ states = out + (size_t)kB * kT * kU; // final h per layer

    // zero xstage once: layer 0 writes only cols 0..7 (F=8); the rest stays 0.
    for (int j = tid; j < 2 * kSt * kU; j += kThreads) xstage[j] = 0.f;

#pragma unroll 1
    for (int l = 0; l < kL; ++l) {
        // ---- weights -> registers (once per layer), lane->consecutive cols ----
        float whA[32], whB[32];  // rec_k rows 32kq+i, cols c / c+192
        float wxA[32], wxB[32];  // input kernel, same tile
        {
            const float* Wh = rec_k + (size_t)l * kU * kG;
#pragma unroll
            for (int i = 0; i < 32; ++i) {
                const float* p = Wh + (size_t)(32 * kq + i) * kG;
                whA[i] = p[c]; whB[i] = p[192 + c];
            }
        }
        if (l == 0) {
#pragma unroll
            for (int i = 0; i < 32; ++i) { wxA[i] = 0.f; wxB[i] = 0.f; }
            if (kq == 0) {
#pragma unroll
                for (int i = 0; i < kF; ++i) {
                    const float* p = kernel0 + (size_t)i * kG;
                    wxA[i] = p[c]; wxB[i] = p[192 + c];
                }
            }
        } else {
            const float* Wx = kernels + (size_t)(l - 1) * kU * kG;
#pragma unroll
            for (int i = 0; i < 32; ++i) {
                const float* p = Wx + (size_t)(32 * kq + i) * kG;
                wxA[i] = p[c]; wxB[i] = p[192 + c];
            }
        }
        // biases -> LDS (768 threads = exactly 2*384)
        if (tid < kG) biasx[tid]      = biases[(size_t)l * 2 * kG + tid];
        else          biash[tid - kG] = biases[(size_t)l * 2 * kG + tid];
        if (tid < kRows * kU)
            hbuf[tid] = init_h[(size_t)l * kB * kU + (size_t)(b0 + gr) * kU + gu];
        __syncthreads();

#pragma unroll 1
        for (int t0 = 0; t0 < kT; t0 += kSt) {
            // ---- X1: stage x for the next 8 steps ----
            if (l == 0) {
                if (tid < 32) {
                    const int r = tid >> 4, tt = (tid >> 1) & 7, cc = tid & 1;
                    *(float4*)&xstage[(r * kSt + tt) * kU + 4 * cc] =
                        *(const float4*)(xin + ((size_t)(b0 + r) * kT + (t0 + tt)) * kF + 4 * cc);
                }
            } else if (tid < 512) {
                const int r = tid >> 8, rest = tid & 255, tt = rest >> 5, cc = rest & 31;
                *(float4*)&xstage[(r * kSt + tt) * kU + 4 * cc] =
                    *(const float4*)(buf + ((size_t)(b0 + r) * kT + (t0 + tt)) * kU + 4 * cc);
            }
            __syncthreads();

            // ---- 8 recurrence steps: registers + LDS only ----
#pragma unroll 1
            for (int tt = 0; tt < kSt; ++tt) {
                {
                    const float4* xs0 = (const float4*)&xstage[tt * kU + 32 * kq];
                    const float4* xs1 = (const float4*)&xstage[(kSt + tt) * kU + 32 * kq];
                    const float4* hs0 = (const float4*)&hbuf[32 * kq];
                    const float4* hs1 = (const float4*)&hbuf[kU + 32 * kq];
                    float axA0 = 0.f, axA1 = 0.f, ahA0 = 0.f, ahA1 = 0.f;
                    float axB0 = 0.f, axB1 = 0.f, ahB0 = 0.f, ahB1 = 0.f;
                    if (l == 0) {
                        DOT_H(0) DOT_H(1) DOT_H(2) DOT_H(3)
                        DOT_H(4) DOT_H(5) DOT_H(6) DOT_H(7)
                        if (kq == 0) { DOT_X(0) DOT_X(1) }  // F=8: rows 0..7 only
                    } else {
                        DOT_H(0) DOT_X(0) DOT_H(1) DOT_X(1)
                        DOT_H(2) DOT_X(2) DOT_H(3) DOT_X(3)
                        DOT_H(4) DOT_X(4) DOT_H(5) DOT_X(5)
                        DOT_H(6) DOT_X(6) DOT_H(7) DOT_X(7)
                    }
                    float* px0 = pacc + (size_t)((kq * 2 + 0) * 2 + 0) * kG;
                    float* p1x = pacc + (size_t)((kq * 2 + 1) * 2 + 0) * kG;
                    float* ph0 = pacc + (size_t)((kq * 2 + 0) * 2 + 1) * kG;
                    float* p1h = pacc + (size_t)((kq * 2 + 1) * 2 + 1) * kG;
                    px0[c] = axA0; px0[192 + c] = axB0;
                    p1x[c] = axA1; p1x[192 + c] = axB1;
                    ph0[c] = ahA0; ph0[192 + c] = ahB0;
                    p1h[c] = ahA1; p1h[192 + c] = ahB1;
                }
                __syncthreads();

                // ---- gates: threads 0..255 = (row, unit) ----
                if (tid < kRows * kU) {
                    float sz = 0.f, sr = 0.f, sxh = 0.f, shh = 0.f;
#pragma unroll
                    for (int k2 = 0; k2 < 4; ++k2) {
                        const float* px = pacc + (size_t)((k2 * 2 + gr) * 2 + 0) * kG;
                        const float* ph = pacc + (size_t)((k2 * 2 + gr) * 2 + 1) * kG;
                        sz  += px[gu] + ph[gu];
                        sr  += px[kU + gu] + ph[kU + gu];
                        sxh += px[2 * kU + gu];
                        shh += ph[2 * kU + gu];
                    }
                    const float z  = frcp(1.f + __expf(-(sz + biasx[gu] + biash[gu])));
                    const float rg = frcp(1.f + __expf(-(sr + biasx[kU + gu] + biash[kU + gu])));
                    const float ta = sxh + biasx[2 * kU + gu] + rg * (shh + biash[2 * kU + gu]);
                    const float hh = 1.f - 2.f * frcp(1.f + __expf(2.f * ta));  // tanh
                    const float h  = z * hbuf[gr * kU + gu] + (1.f - z) * hh;
                    hbuf[gr * kU + gu] = h;
                    buf[((size_t)(b0 + gr) * kT + (t0 + tt)) * kU + gu] = h;
                }
                __syncthreads();
            }
        }

        // ---- final state of this layer ----
        if (tid < kRows * kU)
            states[(size_t)l * kB * kU + (size_t)(b0 + gr) * kU + gu] = hbuf[tid];
        __syncthreads();
    }
}

}  // namespace

extern "C" void kernel_launch(void* const* d_in, const int* in_sizes, int n_in,
                              void* d_out, int out_size, void* d_ws, size_t ws_size,
                              hipStream_t stream) {
    const float* xin     = (const float*)d_in[0];
    const float* init_h  = (const float*)d_in[1];
    const float* kernel0 = (const float*)d_in[2];
    const float* kernels = (const float*)d_in[3];
    const float* rec_k   = (const float*)d_in[4];
    const float* biases  = (const float*)d_in[5];
    float* out = (float*)d_out;

    dim3 grid(kB / kRows);   // 256 blocks, 1 per CU
    dim3 block(kThreads);    // 768 threads = 12 waves, 3 per SIMD
    gru_all<<<grid, block, 0, stream>>>(xin, init_h, kernel0, kernels, rec_k, biases, out);
}

// Round 4
// 4212.272 us; speedup vs baseline: 13.4564x; 13.4564x over previous
//
#include <hip/hip_runtime.h>
#include <math.h>

// SynchronGRU R11: resident h-weights ONLY + time-batched x-GEMM through LDS.
// R10 post-mortem: 128 resident floats/thread at the 170-VGPR cap made the RA
// dump the weight arrays to SCRATCH (VGPR_Count 84, FETCH 124 GB, 56 ms).
// R9: 192 resident -> AGPR-move tax (2.3x VALU floor). R8: 96 resident at a
// 256 cap was clean. Conclusion: both matrices resident = 77% of the CU
// register file -- never clean. Only W_h is needed every step.
// R11 (768 thr, 12 waves):
//  - W_h resident: 64 floats/thread (kq = wave&3 k-quarter; cols {ch,192+ch}).
//    128 FMA/thread/step, register-only.
//  - x-projection = time-batched GEMM (M = 2 rows x 16 steps): W_x staged
//    k-tile-by-k-tile (32x384 = 48 KB) into LDS once per 16-step chunk; each
//    LDS W-read feeds 16 FMAs; results -> xg[2][16][384] in LDS. W_x L2
//    traffic drops to 3.2 GB total. No xpart, no reduce pass.
//  - gate phase (256 thr) reads xg + 4 h-partials, in-LDS h, global h write.
// Per-step/CU: ~1740 cy VALU vs 1536-cy pure-FMA floor. LDS 128 KB, 1 blk/CU.

namespace {

constexpr int kB = 512;
constexpr int kT = 256;
constexpr int kF = 8;
constexpr int kU = 128;
constexpr int kG = 384;   // 3*U, gate order [z, r, h]
constexpr int kL = 8;
constexpr int kRows = 2;       // batch rows per block
constexpr int kThreads = 768;  // 12 waves, 3 per SIMD
constexpr int kSt = 16;        // time-steps per chunk (x-GEMM M = 32)

// LDS layout (floats)
constexpr int kOffXstage = 0;            // [2][16][128] = 4096
constexpr int kOffWlds   = 4096;         // [32][384]    = 12288 (one k-tile)
constexpr int kOffXg     = 16384;        // [2][16][384] = 12288
constexpr int kOffHbuf   = 28672;        // [2][128]     = 256
constexpr int kOffPacc   = 28928;        // [4kq][2r][384] = 3072
constexpr int kOffBiasx  = 32000;        // [384]
constexpr int kOffBiash  = 32384;        // [384]
constexpr int kSmemFloats = 32768;       // 128 KB
static_assert(kSmemFloats * 4 <= 160 * 1024, "LDS budget");

__device__ __forceinline__ float frcp(float x) { return __builtin_amdgcn_rcpf(x); }

__global__ __launch_bounds__(kThreads, 3) void gru_all(
    const float* __restrict__ xin,      // (B,T,F)
    const float* __restrict__ init_h,   // (L,B,U)
    const float* __restrict__ kernel0,  // (F,3U)
    const float* __restrict__ kernels,  // (L-1,U,3U)
    const float* __restrict__ rec_k,    // (L,U,3U)
    const float* __restrict__ biases,   // (L,2,3U)
    float* __restrict__ out)            // (B,T,U) seq out | (L,B,U) states
{
    __shared__ __align__(16) float smem[kSmemFloats];
    float* xstage = smem + kOffXstage;
    float* Wlds   = smem + kOffWlds;
    float* xg     = smem + kOffXg;
    float* hbuf   = smem + kOffHbuf;
    float* pacc   = smem + kOffPacc;
    float* biasx  = smem + kOffBiasx;
    float* biash  = smem + kOffBiash;

    const int tid  = threadIdx.x;
    const int b0   = blockIdx.x * kRows;
    const int lane = tid & 63;
    const int wv   = tid >> 6;
    // h-identity: wave-uniform k-quarter, owns cols {ch, 192+ch}
    const int kq = wv & 3;
    const int ch = ((wv >> 2) << 6) + lane;  // 0..191
    // x-identity: batch row + single column
    const int xr = (tid >= kG) ? 1 : 0;
    const int xc = tid - kG * xr;            // 0..383
    // gate identity (valid tid<256)
    const int gr = (tid >> 7) & 1;
    const int gu = tid & 127;

    float* __restrict__ buf    = out;                        // in-place activations
    float* __restrict__ states = out + (size_t)kB * kT * kU; // final h per layer

#pragma unroll 1
    for (int l = 0; l < kL; ++l) {
        // ---- W_h -> registers (once per layer): 64 floats/thread ----
        float whA[32], whB[32];
        {
            const float* Wh = rec_k + (size_t)l * kU * kG;
#pragma unroll
            for (int i = 0; i < 32; ++i) {
                const float* p = Wh + (size_t)(32 * kq + i) * kG;
                whA[i] = p[ch]; whB[i] = p[192 + ch];
            }
        }
        if (tid < kG) biasx[tid]      = biases[(size_t)l * 2 * kG + tid];
        else          biash[tid - kG] = biases[(size_t)l * 2 * kG + tid];
        if (tid < kRows * kU)
            hbuf[tid] = init_h[(size_t)l * kB * kU + (size_t)(b0 + gr) * kU + gu];
        __syncthreads();

        const int nkt = (l == 0) ? 1 : 4;  // k-tiles of 32 (l0: K=8)
        const int nk4 = (l == 0) ? 2 : 8;  // k-quads per tile

#pragma unroll 1
        for (int t0 = 0; t0 < kT; t0 += kSt) {
            // ---- X1: stage x for the next 16 steps ----
            if (l == 0) {
                if (tid < 64) {
                    const int r = tid >> 5, q = tid & 31, tt = q >> 1, hf = q & 1;
                    *(float4*)&xstage[(r * kSt + tt) * kU + 4 * hf] =
                        *(const float4*)(xin + ((size_t)(b0 + r) * kT + (t0 + tt)) * kF + 4 * hf);
                }
            } else {
#pragma unroll
                for (int i = tid; i < 1024; i += kThreads) {
                    const int r = i >> 9, idx = i & 511, tt = idx >> 5, c4 = idx & 31;
                    *(float4*)&xstage[(r * kSt + tt) * kU + 4 * c4] =
                        *(const float4*)(buf + ((size_t)(b0 + r) * kT + (t0 + tt)) * kU + 4 * c4);
                }
            }

            // ---- X2: time-batched x-GEMM (M=32), W_x via LDS k-tiles ----
            {
                float acc[kSt];
#pragma unroll
                for (int i = 0; i < kSt; ++i) acc[i] = 0.f;

#pragma unroll 1
                for (int kt = 0; kt < nkt; ++kt) {
                    __syncthreads();  // Wlds free (prev readers done) + xstage ready
                    if (l == 0) {
                        const int row = tid / 96, c4 = tid % 96;  // 8 rows x 96 quads
                        *(float4*)&Wlds[row * kG + 4 * c4] =
                            *(const float4*)(kernel0 + (size_t)row * kG + 4 * c4);
                    } else {
                        const float* Wx = kernels + (size_t)(l - 1) * kU * kG;
#pragma unroll
                        for (int j = 0; j < 4; ++j) {
                            const int idx = tid + j * kThreads;
                            const int row = idx / 96, c4 = idx % 96;
                            *(float4*)&Wlds[row * kG + 4 * c4] =
                                *(const float4*)(Wx + (size_t)(kt * 32 + row) * kG + 4 * c4);
                        }
                    }
                    __syncthreads();

#pragma unroll 1
                    for (int k4 = 0; k4 < nk4; ++k4) {
                        const float w0 = Wlds[(4 * k4 + 0) * kG + xc];
                        const float w1 = Wlds[(4 * k4 + 1) * kG + xc];
                        const float w2 = Wlds[(4 * k4 + 2) * kG + xc];
                        const float w3 = Wlds[(4 * k4 + 3) * kG + xc];
#pragma unroll
                        for (int tt = 0; tt < kSt; ++tt) {
                            const float4 x =
                                *(const float4*)&xstage[(xr * kSt + tt) * kU + kt * 32 + 4 * k4];
                            acc[tt] += w0 * x.x;
                            acc[tt] += w1 * x.y;
                            acc[tt] += w2 * x.z;
                            acc[tt] += w3 * x.w;
                        }
                    }
                }
#pragma unroll
                for (int tt = 0; tt < kSt; ++tt)
                    xg[(xr * kSt + tt) * kG + xc] = acc[tt];
            }
            __syncthreads();

            // ---- 16 recurrence steps: register W_h + LDS broadcasts ----
#pragma unroll 1
            for (int tt = 0; tt < kSt; ++tt) {
                {
                    const float4* hs0 = (const float4*)&hbuf[32 * kq];
                    const float4* hs1 = (const float4*)&hbuf[kU + 32 * kq];
                    float a0A = 0.f, a0B = 0.f, a1A = 0.f, a1B = 0.f;
#pragma unroll
                    for (int k4 = 0; k4 < 8; ++k4) {
                        const float4 h0 = hs0[k4];
                        const float4 h1 = hs1[k4];
                        a0A += whA[4 * k4 + 0] * h0.x; a0B += whB[4 * k4 + 0] * h0.x;
                        a1A += whA[4 * k4 + 0] * h1.x; a1B += whB[4 * k4 + 0] * h1.x;
                        a0A += whA[4 * k4 + 1] * h0.y; a0B += whB[4 * k4 + 1] * h0.y;
                        a1A += whA[4 * k4 + 1] * h1.y; a1B += whB[4 * k4 + 1] * h1.y;
                        a0A += whA[4 * k4 + 2] * h0.z; a0B += whB[4 * k4 + 2] * h0.z;
                        a1A += whA[4 * k4 + 2] * h1.z; a1B += whB[4 * k4 + 2] * h1.z;
                        a0A += whA[4 * k4 + 3] * h0.w; a0B += whB[4 * k4 + 3] * h0.w;
                        a1A += whA[4 * k4 + 3] * h1.w; a1B += whB[4 * k4 + 3] * h1.w;
                    }
                    pacc[(kq * 2 + 0) * kG + ch]       = a0A;
                    pacc[(kq * 2 + 0) * kG + 192 + ch] = a0B;
                    pacc[(kq * 2 + 1) * kG + ch]       = a1A;
                    pacc[(kq * 2 + 1) * kG + 192 + ch] = a1B;
                }
                __syncthreads();

                if (tid < kRows * kU) {
                    const float* xgp = &xg[(size_t)(gr * kSt + tt) * kG];
                    float sz = 0.f, sr = 0.f, sp = 0.f;
#pragma unroll
                    for (int k2 = 0; k2 < 4; ++k2) {
                        const float* ph = pacc + (size_t)(k2 * 2 + gr) * kG;
                        sz += ph[gu]; sr += ph[kU + gu]; sp += ph[2 * kU + gu];
                    }
                    const float z  = frcp(1.f + __expf(-(xgp[gu] + biasx[gu] + sz + biash[gu])));
                    const float rg = frcp(1.f + __expf(-(xgp[kU + gu] + biasx[kU + gu] + sr + biash[kU + gu])));
                    const float ta = xgp[2 * kU + gu] + biasx[2 * kU + gu] + rg * (sp + biash[2 * kU + gu]);
                    const float hh = 1.f - 2.f * frcp(1.f + __expf(2.f * ta));  // tanh
                    const float h  = z * hbuf[tid] + (1.f - z) * hh;
                    hbuf[tid] = h;
                    buf[((size_t)(b0 + gr) * kT + (t0 + tt)) * kU + gu] = h;
                }
                __syncthreads();
            }
        }

        // ---- final state of this layer ----
        if (tid < kRows * kU)
            states[(size_t)l * kB * kU + (size_t)(b0 + gr) * kU + gu] = hbuf[tid];
        __syncthreads();
    }
}

}  // namespace

extern "C" void kernel_launch(void* const* d_in, const int* in_sizes, int n_in,
                              void* d_out, int out_size, void* d_ws, size_t ws_size,
                              hipStream_t stream) {
    const float* xin     = (const float*)d_in[0];
    const float* init_h  = (const float*)d_in[1];
    const float* kernel0 = (const float*)d_in[2];
    const float* kernels = (const float*)d_in[3];
    const float* rec_k   = (const float*)d_in[4];
    const float* biases  = (const float*)d_in[5];
    float* out = (float*)d_out;

    dim3 grid(kB / kRows);   // 256 blocks, 1 per CU (128 KB LDS enforces)
    dim3 block(kThreads);    // 768 threads = 12 waves, 3 per SIMD
    gru_all<<<grid, block, 0, stream>>>(xin, init_h, kernel0, kernels, rec_k, biases, out);
}